// Round 4
// baseline (642.267 us; speedup 1.0000x reference)
//
#include <hip/hip_runtime.h>
#include <math.h>

// RouterLite fused pipeline v4 = v2 logic (fp32 inputs, fp32 compute) with the
// output written as FP32 (v1-v3 wrote bf16 ushorts into a buffer the harness
// reads as fp32 — that packing was the sole source of the 0.732 absmax; v3's
// NaN proved inputs are fp32, not bf16).
//
// ws map (floats), total ~31.8 MB:
//   stats [8192][2]        LN mean/rstd (q rows then R rows)
//   H     [8192][256]      GELU(LN(x)@W1^T + b1)
//   Z     [8192][128]      l2n(mlp): rows 0..4095 = z_q, 4096.. = Z_r
//   LP    [8][4096][2]     per-colsplit partial (l, W)
//   ILW   [4096][2]        per q-row: 1/l, u_n
//   RP    [8][4096][128]   K-split partials of attn@Z_r
//   RB    [4096][128]      r_bar (l2-normalized)
//   COS   [4096]           cos(z_q, r_bar)
// d_out: fp32, [0..4095]=raw_logit, [4096..8191]=delta_theta.

#define HD   2048
#define D2   256
#define DD   128
#define NQ   4096
#define NT   8192

static __device__ __forceinline__ float gelu_exact(float x){
    return 0.5f * x * (1.0f + erff(x * 0.7071067811865475f));
}

// ---------------- K1: LayerNorm statistics for q (rows 0..4095) and R (4096..8191)
__global__ __launch_bounds__(256)
void k1_ln_stats(const float* __restrict__ q, const float* __restrict__ R,
                 float* __restrict__ stats){
    const int r = blockIdx.x;
    const int tid = threadIdx.x;
    const float* src = (r < NQ) ? (q + (size_t)r * HD) : (R + (size_t)(r - NQ) * HD);
    float s = 0.f, sq = 0.f;
#pragma unroll
    for (int i = 0; i < HD / 256; ++i){
        float v = src[tid + i * 256];
        s += v; sq += v * v;
    }
    __shared__ float red[256];
    red[tid] = s; __syncthreads();
    for (int off = 128; off > 0; off >>= 1){
        if (tid < off) red[tid] += red[tid + off];
        __syncthreads();
    }
    float sum = red[0]; __syncthreads();
    red[tid] = sq; __syncthreads();
    for (int off = 128; off > 0; off >>= 1){
        if (tid < off) red[tid] += red[tid + off];
        __syncthreads();
    }
    if (tid == 0){
        float mean = sum * (1.0f / HD);
        float var  = red[0] * (1.0f / HD) - mean * mean;
        var = fmaxf(var, 0.0f);
        stats[2 * r]     = mean;
        stats[2 * r + 1] = rsqrtf(var + 1e-5f);
    }
}

// ---------------- K2: H = GELU(LN(X) @ W1^T + b1), full K in-kernel.
// grid (2 n-blocks, 64 m-blocks, 2 inputs), 256 thr, tile 64x128, acc 4x8.
__global__ __launch_bounds__(256)
void k2_gemm1_gelu(const float* __restrict__ q, const float* __restrict__ R,
                   const float* __restrict__ stats,
                   const float* __restrict__ gq, const float* __restrict__ bq,
                   const float* __restrict__ W1q, const float* __restrict__ b1q,
                   const float* __restrict__ gr, const float* __restrict__ br,
                   const float* __restrict__ W1r, const float* __restrict__ b1r,
                   float* __restrict__ H){
    const int inp = blockIdx.z;
    const int n0  = blockIdx.x * 128;
    const int m0  = blockIdx.y * 64;
    const float* X  = inp ? R   : q;
    const float* g  = inp ? gr  : gq;
    const float* b  = inp ? br  : bq;
    const float* W1 = inp ? W1r : W1q;
    const float* b1 = inp ? b1r : b1q;
    const int rbase = inp * NQ;

    __shared__ __align__(16) float Xs[64][36];
    __shared__ __align__(16) float Wk[32][132];
    __shared__ float meanS[64], rstdS[64];

    const int tid = threadIdx.x;
    if (tid < 64){
        meanS[tid] = stats[2 * (rbase + m0 + tid)];
        rstdS[tid] = stats[2 * (rbase + m0 + tid) + 1];
    }
    __syncthreads();

    const int ty = tid >> 4;
    const int tx = tid & 15;

    float acc[4][8];
#pragma unroll
    for (int i = 0; i < 4; ++i)
#pragma unroll
        for (int jj = 0; jj < 8; ++jj) acc[i][jj] = 0.f;

    for (int kc = 0; kc < 64; ++kc){
        const int k0 = kc * 32;
#pragma unroll
        for (int i = 0; i < 8; ++i){
            int e = tid + i * 256;
            int rr = e >> 5, kk = e & 31;
            float xv = X[(size_t)(m0 + rr) * HD + k0 + kk];
            Xs[rr][kk] = (xv - meanS[rr]) * rstdS[rr] * g[k0 + kk] + b[k0 + kk];
        }
#pragma unroll
        for (int i = 0; i < 16; ++i){
            int e = tid + i * 256;
            int nn = e >> 5, kk = e & 31;
            Wk[kk][nn] = W1[(size_t)(n0 + nn) * HD + k0 + kk];
        }
        __syncthreads();
#pragma unroll
        for (int k4 = 0; k4 < 8; ++k4){
            float a0[4][4];
#pragma unroll
            for (int jj = 0; jj < 4; ++jj){
                float4 t0 = *(const float4*)&Xs[ty * 4 + jj][k4 * 4];
                a0[jj][0] = t0.x; a0[jj][1] = t0.y; a0[jj][2] = t0.z; a0[jj][3] = t0.w;
            }
#pragma unroll
            for (int kq = 0; kq < 4; ++kq){
                float4 w0 = *(const float4*)&Wk[k4 * 4 + kq][tx * 8];
                float4 w1 = *(const float4*)&Wk[k4 * 4 + kq][tx * 8 + 4];
                float wv[8] = {w0.x, w0.y, w0.z, w0.w, w1.x, w1.y, w1.z, w1.w};
#pragma unroll
                for (int i = 0; i < 4; ++i){
#pragma unroll
                    for (int jj = 0; jj < 8; ++jj){
                        acc[i][jj] += a0[i][kq] * wv[jj];
                    }
                }
            }
        }
        __syncthreads();
    }
#pragma unroll
    for (int i = 0; i < 4; ++i){
        int rr = ty * 4 + i;
        size_t o = (size_t)(rbase + m0 + rr) * D2 + n0 + tx * 8;
        float h[8];
#pragma unroll
        for (int jj = 0; jj < 8; ++jj)
            h[jj] = gelu_exact(acc[i][jj] + b1[n0 + tx * 8 + jj]);
        float4 o0 = {h[0], h[1], h[2], h[3]};
        float4 o1 = {h[4], h[5], h[6], h[7]};
        *(float4*)&H[o]     = o0;
        *(float4*)&H[o + 4] = o1;
    }
}

// ---------------- K3: GEMM2 (H @ W2^T + b2) + l2norm -> Z
// grid 256 (32 rows each), 256 thr, acc 2x8, KT=64.
__global__ __launch_bounds__(256)
void k3_gemm2(const float* __restrict__ H,
              const float* __restrict__ W2q, const float* __restrict__ b2q,
              const float* __restrict__ W2r, const float* __restrict__ b2r,
              float* __restrict__ Z){
    const int gstart = blockIdx.x * 32;
    const int inp = (gstart >= NQ) ? 1 : 0;
    const float* W2 = inp ? W2r : W2q;
    const float* b2 = inp ? b2r : b2q;

    __shared__ __align__(16) float Hs[32][68];
    __shared__ __align__(16) float Wk[64][132];
    __shared__ float red[32][17];
    __shared__ float normS[32];

    const int tid = threadIdx.x;
    const int ty = tid >> 4;
    const int tx = tid & 15;

    float acc[2][8];
#pragma unroll
    for (int jj = 0; jj < 8; ++jj){ acc[0][jj] = 0.f; acc[1][jj] = 0.f; }

    for (int kc = 0; kc < 4; ++kc){
#pragma unroll
        for (int i = 0; i < 8; ++i){
            int e = tid + i * 256;
            int rr = e >> 6, kk = e & 63;
            Hs[rr][kk] = H[(size_t)(gstart + rr) * D2 + kc * 64 + kk];
        }
#pragma unroll
        for (int i = 0; i < 32; ++i){
            int e = tid + i * 256;
            int nn = e >> 6, kk = e & 63;
            Wk[kk][nn] = W2[(size_t)nn * D2 + kc * 64 + kk];
        }
        __syncthreads();
#pragma unroll
        for (int k4 = 0; k4 < 16; ++k4){
            float a0[4], a1[4];
            float4 t0 = *(const float4*)&Hs[ty * 2][k4 * 4];
            a0[0] = t0.x; a0[1] = t0.y; a0[2] = t0.z; a0[3] = t0.w;
            float4 t1 = *(const float4*)&Hs[ty * 2 + 1][k4 * 4];
            a1[0] = t1.x; a1[1] = t1.y; a1[2] = t1.z; a1[3] = t1.w;
#pragma unroll
            for (int kq = 0; kq < 4; ++kq){
                float4 w0 = *(const float4*)&Wk[k4 * 4 + kq][tx * 8];
                float4 w1 = *(const float4*)&Wk[k4 * 4 + kq][tx * 8 + 4];
                float wv[8] = {w0.x, w0.y, w0.z, w0.w, w1.x, w1.y, w1.z, w1.w};
#pragma unroll
                for (int jj = 0; jj < 8; ++jj){
                    acc[0][jj] += a0[kq] * wv[jj];
                    acc[1][jj] += a1[kq] * wv[jj];
                }
            }
        }
        __syncthreads();
    }
    float v0[8], v1[8];
    float sq0 = 0.f, sq1 = 0.f;
#pragma unroll
    for (int jj = 0; jj < 8; ++jj){
        int c = tx * 8 + jj;
        v0[jj] = acc[0][jj] + b2[c];
        v1[jj] = acc[1][jj] + b2[c];
        sq0 += v0[jj] * v0[jj];
        sq1 += v1[jj] * v1[jj];
    }
    red[ty * 2][tx]     = sq0;
    red[ty * 2 + 1][tx] = sq1;
    __syncthreads();
    if (tid < 32){
        float s = 0.f;
#pragma unroll
        for (int t = 0; t < 16; ++t) s += red[tid][t];
        normS[tid] = 1.0f / fmaxf(sqrtf(s), 1e-12f);
    }
    __syncthreads();
    float s0 = normS[ty * 2], s1 = normS[ty * 2 + 1];
    size_t o0 = (size_t)(gstart + ty * 2) * DD + tx * 8;
    size_t o1 = (size_t)(gstart + ty * 2 + 1) * DD + tx * 8;
    float4 z00 = {v0[0]*s0, v0[1]*s0, v0[2]*s0, v0[3]*s0};
    float4 z01 = {v0[4]*s0, v0[5]*s0, v0[6]*s0, v0[7]*s0};
    float4 z10 = {v1[0]*s1, v1[1]*s1, v1[2]*s1, v1[3]*s1};
    float4 z11 = {v1[4]*s1, v1[5]*s1, v1[6]*s1, v1[7]*s1};
    *(float4*)&Z[o0]     = z00;
    *(float4*)&Z[o0 + 4] = z01;
    *(float4*)&Z[o1]     = z10;
    *(float4*)&Z[o1 + 4] = z11;
}

// ---------------- K5: per-row softmax sums, recomputing scores from Z.
// grid (8 col-splits, 32 row-blocks), 256 thr. Tile 128 q x 128 r, acc 8x8.
// l = sum e^s, W = sum e^s * s  (no max needed: |s| <= 1/sqrt(128)).
__global__ __launch_bounds__(256)
void k5_stats(const float* __restrict__ Z, float* __restrict__ LP){
    const int split = blockIdx.x;
    const int m0 = blockIdx.y * 128;
    const float* Zq = Z;
    const float* Zr = Z + (size_t)NQ * DD;

    __shared__ __align__(16) float As[128][36];
    __shared__ __align__(16) float Bk[32][132];
    __shared__ float red[128][17];

    const int tid = threadIdx.x;
    const int ty = tid >> 4, tx = tid & 15;
    const float scl = 0.08838834764831845f;  // 1/sqrt(128)

    float lacc[8], wacc[8];
#pragma unroll
    for (int i = 0; i < 8; ++i){ lacc[i] = 0.f; wacc[i] = 0.f; }

    for (int ct = 0; ct < 4; ++ct){
        const int n0 = split * 512 + ct * 128;
        float acc[8][8];
#pragma unroll
        for (int i = 0; i < 8; ++i)
#pragma unroll
            for (int jj = 0; jj < 8; ++jj) acc[i][jj] = 0.f;

        for (int kc = 0; kc < 4; ++kc){
#pragma unroll
            for (int i = 0; i < 16; ++i){
                int e = tid + i * 256;
                int rr = e >> 5, kk = e & 31;
                As[rr][kk] = Zq[(size_t)(m0 + rr) * DD + kc * 32 + kk];
            }
#pragma unroll
            for (int i = 0; i < 16; ++i){
                int e = tid + i * 256;
                int cc = e >> 5, kk = e & 31;
                Bk[kk][cc] = Zr[(size_t)(n0 + cc) * DD + kc * 32 + kk];
            }
            __syncthreads();
#pragma unroll
            for (int k4 = 0; k4 < 8; ++k4){
                float a0[4][4], a1[4][4];
#pragma unroll
                for (int jj = 0; jj < 4; ++jj){
                    float4 t0 = *(const float4*)&As[ty * 4 + jj][k4 * 4];
                    a0[jj][0] = t0.x; a0[jj][1] = t0.y; a0[jj][2] = t0.z; a0[jj][3] = t0.w;
                    float4 t1 = *(const float4*)&As[64 + ty * 4 + jj][k4 * 4];
                    a1[jj][0] = t1.x; a1[jj][1] = t1.y; a1[jj][2] = t1.z; a1[jj][3] = t1.w;
                }
#pragma unroll
                for (int kq = 0; kq < 4; ++kq){
                    float4 b0 = *(const float4*)&Bk[k4 * 4 + kq][tx * 4];
                    float4 b1 = *(const float4*)&Bk[k4 * 4 + kq][64 + tx * 4];
                    float bv[8] = {b0.x, b0.y, b0.z, b0.w, b1.x, b1.y, b1.z, b1.w};
#pragma unroll
                    for (int i = 0; i < 4; ++i){
#pragma unroll
                        for (int jj = 0; jj < 8; ++jj){
                            acc[i][jj]     += a0[i][kq] * bv[jj];
                            acc[4 + i][jj] += a1[i][kq] * bv[jj];
                        }
                    }
                }
            }
            __syncthreads();
        }
#pragma unroll
        for (int i = 0; i < 8; ++i){
#pragma unroll
            for (int jj = 0; jj < 8; ++jj){
                float s = acc[i][jj] * scl;
                float e = __expf(s);
                lacc[i] += e;
                wacc[i] += e * s;
            }
        }
    }
#pragma unroll
    for (int i = 0; i < 8; ++i){
        int rr = (i < 4) ? (ty * 4 + i) : (64 + ty * 4 + (i - 4));
        red[rr][tx] = lacc[i];
    }
    __syncthreads();
    if (tid < 128){
        float l = 0.f;
#pragma unroll
        for (int t = 0; t < 16; ++t) l += red[tid][t];
        LP[((size_t)split * NQ + m0 + tid) * 2] = l;
    }
    __syncthreads();
#pragma unroll
    for (int i = 0; i < 8; ++i){
        int rr = (i < 4) ? (ty * 4 + i) : (64 + ty * 4 + (i - 4));
        red[rr][tx] = wacc[i];
    }
    __syncthreads();
    if (tid < 128){
        float w = 0.f;
#pragma unroll
        for (int t = 0; t < 16; ++t) w += red[tid][t];
        LP[((size_t)split * NQ + m0 + tid) * 2 + 1] = w;
    }
}

// ---------------- K5b: combine split sums -> 1/l and u_n.
__global__ __launch_bounds__(256)
void k5b_combine(const float* __restrict__ LP, float* __restrict__ ILW){
    const int r = blockIdx.x * 256 + threadIdx.x;
    float l = 0.f, w = 0.f;
#pragma unroll
    for (int s = 0; s < 8; ++s){
        l += LP[((size_t)s * NQ + r) * 2];
        w += LP[((size_t)s * NQ + r) * 2 + 1];
    }
    float il = 1.0f / l;
    float ent = logf(l) - w * il;   // = -sum p ln p
    ILW[2 * r]     = il;
    ILW[2 * r + 1] = ent * (1.0f / 8.317766166719343f);  // / ln(4096)
}

// ---------------- K6: RP[kz] = attn[:, kz-slice] @ Zr[kz-slice], scores recomputed.
// grid (64 row-blocks, 8 K-splits), 128 thr. 64 q-rows; r-chunks of 32.
__global__ __launch_bounds__(128)
void k6_pv(const float* __restrict__ Z, const float* __restrict__ ILW,
           float* __restrict__ RP){
    const int rows0 = blockIdx.x * 64;
    const int kz = blockIdx.y;
    const float* Zq = Z;
    const float* Zr = Z + (size_t)NQ * DD;

    __shared__ __align__(16) float Zqs[64][132];
    __shared__ __align__(16) float Zs[32][132];
    __shared__ __align__(16) float Ps[64][36];
    __shared__ float ilS[64];

    const int tid = threadIdx.x;
    if (tid < 64) ilS[tid] = ILW[2 * (rows0 + tid)];
#pragma unroll
    for (int i = 0; i < 16; ++i){
        int e = tid + i * 128;
        int rr = e >> 5, c4 = e & 31;
        *(float4*)&Zqs[rr][c4 * 4] = *(const float4*)&Zq[(size_t)(rows0 + rr) * DD + c4 * 4];
    }

    const int sy = tid >> 3;   // 0..15 -> 4 q rows each
    const int sx = tid & 7;    // 0..7  -> 4 r cols each
    const int ty = tid >> 4;   // 0..7
    const int tx = tid & 15;
    const float scl = 0.08838834764831845f;

    float acc[8][8];
#pragma unroll
    for (int i = 0; i < 8; ++i)
#pragma unroll
        for (int jj = 0; jj < 8; ++jj) acc[i][jj] = 0.f;

    for (int it = 0; it < 16; ++it){
        const int kt = kz * 512 + it * 32;
#pragma unroll
        for (int i = 0; i < 8; ++i){
            int e = tid + i * 128;
            int rr = e >> 5, c4 = e & 31;
            *(float4*)&Zs[rr][c4 * 4] = *(const float4*)&Zr[(size_t)(kt + rr) * DD + c4 * 4];
        }
        __syncthreads();
        {
            float sacc[4][4];
#pragma unroll
            for (int a = 0; a < 4; ++a)
#pragma unroll
                for (int c = 0; c < 4; ++c) sacc[a][c] = 0.f;
#pragma unroll
            for (int d4 = 0; d4 < 32; ++d4){
                float4 qa[4], rb[4];
#pragma unroll
                for (int a = 0; a < 4; ++a)
                    qa[a] = *(const float4*)&Zqs[sy * 4 + a][d4 * 4];
#pragma unroll
                for (int c = 0; c < 4; ++c)
                    rb[c] = *(const float4*)&Zs[sx * 4 + c][d4 * 4];
#pragma unroll
                for (int a = 0; a < 4; ++a){
#pragma unroll
                    for (int c = 0; c < 4; ++c){
                        sacc[a][c] += qa[a].x * rb[c].x + qa[a].y * rb[c].y
                                    + qa[a].z * rb[c].z + qa[a].w * rb[c].w;
                    }
                }
            }
#pragma unroll
            for (int a = 0; a < 4; ++a){
                float ilr = ilS[sy * 4 + a];
#pragma unroll
                for (int c = 0; c < 4; ++c){
                    Ps[sy * 4 + a][sx * 4 + c] = __expf(sacc[a][c] * scl) * ilr;
                }
            }
        }
        __syncthreads();
#pragma unroll
        for (int k4 = 0; k4 < 8; ++k4){
            float a0[4][4], a1[4][4];
#pragma unroll
            for (int jj = 0; jj < 4; ++jj){
                float4 t0 = *(const float4*)&Ps[ty * 4 + jj][k4 * 4];
                a0[jj][0] = t0.x; a0[jj][1] = t0.y; a0[jj][2] = t0.z; a0[jj][3] = t0.w;
                float4 t1 = *(const float4*)&Ps[32 + ty * 4 + jj][k4 * 4];
                a1[jj][0] = t1.x; a1[jj][1] = t1.y; a1[jj][2] = t1.z; a1[jj][3] = t1.w;
            }
#pragma unroll
            for (int kq = 0; kq < 4; ++kq){
                float4 z0 = *(const float4*)&Zs[k4 * 4 + kq][tx * 8];
                float4 z1 = *(const float4*)&Zs[k4 * 4 + kq][tx * 8 + 4];
                float zv[8] = {z0.x, z0.y, z0.z, z0.w, z1.x, z1.y, z1.z, z1.w};
#pragma unroll
                for (int i = 0; i < 4; ++i){
#pragma unroll
                    for (int jj = 0; jj < 8; ++jj){
                        acc[i][jj]     += a0[i][kq] * zv[jj];
                        acc[4 + i][jj] += a1[i][kq] * zv[jj];
                    }
                }
            }
        }
        __syncthreads();
    }
#pragma unroll
    for (int i = 0; i < 8; ++i){
        int rr = (i < 4) ? (ty * 4 + i) : (32 + ty * 4 + (i - 4));
        size_t o = ((size_t)kz * NQ + rows0 + rr) * DD + tx * 8;
        float4 o0 = {acc[i][0], acc[i][1], acc[i][2], acc[i][3]};
        float4 o1 = {acc[i][4], acc[i][5], acc[i][6], acc[i][7]};
        *(float4*)&RP[o]     = o0;
        *(float4*)&RP[o + 4] = o1;
    }
}

// ---------------- K6b: combine K-splits, l2norm -> r_bar, cos(z_q, r_bar)
__global__ __launch_bounds__(128)
void k6b_combine(const float* __restrict__ RP, const float* __restrict__ Z,
                 float* __restrict__ RB, float* __restrict__ COS){
    const int r = blockIdx.x;
    const int c = threadIdx.x;
    float v = 0.f;
#pragma unroll
    for (int s = 0; s < 8; ++s) v += RP[((size_t)s * NQ + r) * DD + c];
    __shared__ float red[128];
    red[c] = v * v; __syncthreads();
    for (int off = 64; off > 0; off >>= 1){
        if (c < off) red[c] += red[c + off];
        __syncthreads();
    }
    float scale = 1.0f / fmaxf(sqrtf(red[0]), 1e-12f);
    __syncthreads();
    float rb = v * scale;
    RB[(size_t)r * DD + c] = rb;
    float zq = Z[(size_t)r * DD + c];
    red[c] = zq * rb; __syncthreads();
    for (int off = 64; off > 0; off >>= 1){
        if (c < off) red[c] += red[c + off];
        __syncthreads();
    }
    if (c == 0) COS[r] = red[0];
}

// ---------------- K8: decoder MLP (LN -> 256->128 GELU -> 128->1) + scalar heads
// grid 256 (16 rows), 256 thr. FP32 output.
__global__ __launch_bounds__(256)
void k8_decoder(const float* __restrict__ Z, const float* __restrict__ RB,
                const float* __restrict__ ILW, const float* __restrict__ COS,
                const float* __restrict__ gd, const float* __restrict__ bd,
                const float* __restrict__ W1d, const float* __restrict__ b1d,
                const float* __restrict__ W2d, const float* __restrict__ b2d,
                const float* __restrict__ beta, const float* __restrict__ W_len,
                const float* __restrict__ b_len,
                float* __restrict__ out){
    const int r0 = blockIdx.x * 16;
    const int tid = threadIdx.x;

    __shared__ __align__(16) float Xk[256][20];   // [feature][row]
    __shared__ __align__(16) float Wd[32][132];
    __shared__ float Hd[16][132];
    __shared__ float red1[16][17], red2[16][17];
    __shared__ float mS[16], rS[16];

#pragma unroll
    for (int i = 0; i < 16; ++i){
        int e = tid + i * 256;
        int rr = e >> 8, cc = e & 255;
        float v = (cc < DD) ? Z[(size_t)(r0 + rr) * DD + cc]
                            : RB[(size_t)(r0 + rr) * DD + (cc - DD)];
        Xk[cc][rr] = v;
    }
    __syncthreads();
    {
        const int row = tid >> 4, sub = tid & 15;
        float s = 0.f, sq = 0.f;
#pragma unroll
        for (int i = 0; i < 16; ++i){
            float v = Xk[sub + 16 * i][row];
            s += v; sq += v * v;
        }
        red1[row][sub] = s; red2[row][sub] = sq;
        __syncthreads();
        if (sub == 0){
            float ts = 0.f, tq = 0.f;
#pragma unroll
            for (int t = 0; t < 16; ++t){ ts += red1[row][t]; tq += red2[row][t]; }
            float mean = ts * (1.0f / D2);
            float var  = tq * (1.0f / D2) - mean * mean;
            var = fmaxf(var, 0.f);
            mS[row] = mean; rS[row] = rsqrtf(var + 1e-5f);
        }
        __syncthreads();
    }
#pragma unroll
    for (int i = 0; i < 16; ++i){
        int e = tid + i * 256;
        int rr = e >> 8, cc = e & 255;
        float v = Xk[cc][rr];
        Xk[cc][rr] = (v - mS[rr]) * rS[rr] * gd[cc] + bd[cc];
    }
    __syncthreads();

    const int j  = tid & 127;
    const int rh = tid >> 7;
    float hacc[8];
    {
        float bj = b1d[j];
#pragma unroll
        for (int i = 0; i < 8; ++i) hacc[i] = bj;
    }
    for (int kc = 0; kc < 8; ++kc){
#pragma unroll
        for (int i = 0; i < 16; ++i){
            int e = tid + i * 256;
            int nn = e >> 5, kk = e & 31;
            Wd[kk][nn] = W1d[(size_t)nn * D2 + kc * 32 + kk];
        }
        __syncthreads();
#pragma unroll
        for (int k = 0; k < 32; ++k){
            float w = Wd[k][j];
            int kk = kc * 32 + k;
            float4 x0 = *(const float4*)&Xk[kk][rh * 8];
            float4 x1 = *(const float4*)&Xk[kk][rh * 8 + 4];
            hacc[0] += x0.x * w; hacc[1] += x0.y * w;
            hacc[2] += x0.z * w; hacc[3] += x0.w * w;
            hacc[4] += x1.x * w; hacc[5] += x1.y * w;
            hacc[6] += x1.z * w; hacc[7] += x1.w * w;
        }
        __syncthreads();
    }
#pragma unroll
    for (int i = 0; i < 8; ++i) Hd[rh * 8 + i][j] = gelu_exact(hacc[i]);
    __syncthreads();
    {
        const int row = tid >> 4, sub = tid & 15;
        float part = 0.f;
#pragma unroll
        for (int i = 0; i < 8; ++i){
            int jj = sub + 16 * i;
            part += Hd[row][jj] * W2d[jj];
        }
        red1[row][sub] = part;
        __syncthreads();
        if (sub == 0){
            float lg = b2d[0];
#pragma unroll
            for (int t = 0; t < 16; ++t) lg += red1[row][t];
            int gr = r0 + row;
            float u  = ILW[2 * gr + 1];
            float cv = COS[gr];
            float dln = cv * W_len[0] + u * W_len[1] + b_len[0];
            float dt = beta[0] * u + beta[1] * tanhf(dln);
            dt = fminf(0.5f, fmaxf(-0.5f, dt));
            out[gr]      = lg;
            out[NQ + gr] = dt;
        }
    }
}

extern "C" void kernel_launch(void* const* d_in, const int* in_sizes, int n_in,
                              void* d_out, int out_size, void* d_ws, size_t ws_size,
                              hipStream_t stream){
    const float* q      = (const float*)d_in[0];
    const float* R      = (const float*)d_in[1];
    const float* ln_q_g = (const float*)d_in[2];
    const float* ln_q_b = (const float*)d_in[3];
    const float* W1q    = (const float*)d_in[4];
    const float* b1q    = (const float*)d_in[5];
    const float* W2q    = (const float*)d_in[6];
    const float* b2q    = (const float*)d_in[7];
    const float* ln_r_g = (const float*)d_in[8];
    const float* ln_r_b = (const float*)d_in[9];
    const float* W1r    = (const float*)d_in[10];
    const float* b1r    = (const float*)d_in[11];
    const float* W2r    = (const float*)d_in[12];
    const float* b2r    = (const float*)d_in[13];
    const float* ln_d_g = (const float*)d_in[14];
    const float* ln_d_b = (const float*)d_in[15];
    const float* W1d    = (const float*)d_in[16];
    const float* b1d    = (const float*)d_in[17];
    const float* W2d    = (const float*)d_in[18];
    const float* b2d    = (const float*)d_in[19];
    const float* beta   = (const float*)d_in[20];
    const float* W_len  = (const float*)d_in[21];
    const float* b_len  = (const float*)d_in[22];

    float* WS    = (float*)d_ws;
    float* stats = WS;                                    // 16384
    float* H     = WS + 16384;                            // 8192*256
    float* Z     = H + (size_t)NT * D2;                   // 8192*128
    float* LP    = Z + (size_t)NT * DD;                   // 8*4096*2
    float* ILW   = LP + (size_t)16 * NQ;                  // 4096*2
    float* RP    = ILW + (size_t)2 * NQ;                  // 8*4096*128
    float* RB    = RP + (size_t)8 * NQ * DD;              // 4096*128
    float* COSV  = RB + (size_t)NQ * DD;                  // 4096
    float* out   = (float*)d_out;

    hipLaunchKernelGGL(k1_ln_stats, dim3(NT), dim3(256), 0, stream, q, R, stats);
    hipLaunchKernelGGL(k2_gemm1_gelu, dim3(2, 64, 2), dim3(256), 0, stream,
                       q, R, stats, ln_q_g, ln_q_b, W1q, b1q, ln_r_g, ln_r_b, W1r, b1r, H);
    hipLaunchKernelGGL(k3_gemm2, dim3(256), dim3(256), 0, stream,
                       H, W2q, b2q, W2r, b2r, Z);
    hipLaunchKernelGGL(k5_stats, dim3(8, 32), dim3(256), 0, stream, Z, LP);
    hipLaunchKernelGGL(k5b_combine, dim3(16), dim3(256), 0, stream, LP, ILW);
    hipLaunchKernelGGL(k6_pv, dim3(64, 8), dim3(128), 0, stream, Z, ILW, RP);
    hipLaunchKernelGGL(k6b_combine, dim3(NQ), dim3(128), 0, stream, RP, Z, RB, COSV);
    hipLaunchKernelGGL(k8_decoder, dim3(256), dim3(256), 0, stream,
                       Z, RB, ILW, COSV, ln_d_g, ln_d_b, W1d, b1d, W2d, b2d,
                       beta, W_len, b_len, out);
}

// Round 6
// 451.266 us; speedup vs baseline: 1.4233x; 1.4233x over previous
//
#include <hip/hip_runtime.h>
#include <math.h>

// RouterLite v5.1 = v5 with the k2 launch grid fixed (dim3(2,64,2); the
// dim3(2,128,2) in v5 read 32MB past q and crashed).
// v4 (passed, 642us) + flash-style MFMA attention: k5/k5b/k6/k6b (≈360us
// fp32-vector) replaced by kA_attn (bf16 MFMA) + kC.
// Trick: r_bar = l2n(sum_r e^s z_r) — softmax 1/l cancels in l2n, so PV needs
// no stats; entropy sums (l = Σe^s, W = Σe^s·s) accumulate in the same pass
// (|s| <= 1/sqrt(128), no max-subtraction needed).
//
// ws map (float offsets), total ~26.6 MB:
//   stats  @0        [8192][2]
//   Z      @16384    [8192][128] fp32
//   Zbf    @1064960  [8192][128] bf16 (as 524288 floats)
//   ZbfT   @1589248  [128][4096] bf16 of Z_r, transposed (262144 floats)
//   RB     @1851392  [4096][128]
//   COS    @2375680  [4096]
//   ILW    @2379776  [4096][2]  (only [2r+1]=u_n consumed)
//   UNION  @2387968  H [8192][256] (k2->k3, dead after)  ALIASED WITH
//                    OP [8][4096][128] + LW [8][4096][2] (kA->kC)
// d_out: fp32, [0..4095]=raw_logit, [4096..8191]=delta_theta.

#define HD   2048
#define D2   256
#define DD   128
#define NQ   4096
#define NT   8192

typedef __attribute__((ext_vector_type(8))) short s16x8;
typedef __attribute__((ext_vector_type(4))) float f32x4;

static __device__ __forceinline__ float gelu_exact(float x){
    return 0.5f * x * (1.0f + erff(x * 0.7071067811865475f));
}
static __device__ __forceinline__ unsigned short f2bf(float f){
    unsigned int u = __float_as_uint(f);
    return (unsigned short)((u + 0x7FFFu + ((u >> 16) & 1u)) >> 16);
}
static __device__ __forceinline__ unsigned int pack2bf(float a, float b){
    return (unsigned int)f2bf(a) | ((unsigned int)f2bf(b) << 16);
}

// ---------------- K1: LayerNorm statistics for q (rows 0..4095) and R (4096..8191)
__global__ __launch_bounds__(256)
void k1_ln_stats(const float* __restrict__ q, const float* __restrict__ R,
                 float* __restrict__ stats){
    const int r = blockIdx.x;
    const int tid = threadIdx.x;
    const float* src = (r < NQ) ? (q + (size_t)r * HD) : (R + (size_t)(r - NQ) * HD);
    float s = 0.f, sq = 0.f;
#pragma unroll
    for (int i = 0; i < HD / 256; ++i){
        float v = src[tid + i * 256];
        s += v; sq += v * v;
    }
    __shared__ float red[256];
    red[tid] = s; __syncthreads();
    for (int off = 128; off > 0; off >>= 1){
        if (tid < off) red[tid] += red[tid + off];
        __syncthreads();
    }
    float sum = red[0]; __syncthreads();
    red[tid] = sq; __syncthreads();
    for (int off = 128; off > 0; off >>= 1){
        if (tid < off) red[tid] += red[tid + off];
        __syncthreads();
    }
    if (tid == 0){
        float mean = sum * (1.0f / HD);
        float var  = red[0] * (1.0f / HD) - mean * mean;
        var = fmaxf(var, 0.0f);
        stats[2 * r]     = mean;
        stats[2 * r + 1] = rsqrtf(var + 1e-5f);
    }
}

// ---------------- K2: H = GELU(LN(X) @ W1^T + b1) (fp32 vector; MFMA port next)
// grid (2 n-blocks, 64 m-blocks, 2 inputs), 256 thr, tile 64x128, acc 4x8.
__global__ __launch_bounds__(256)
void k2_gemm1_gelu(const float* __restrict__ q, const float* __restrict__ R,
                   const float* __restrict__ stats,
                   const float* __restrict__ gq, const float* __restrict__ bq,
                   const float* __restrict__ W1q, const float* __restrict__ b1q,
                   const float* __restrict__ gr, const float* __restrict__ br,
                   const float* __restrict__ W1r, const float* __restrict__ b1r,
                   float* __restrict__ H){
    const int inp = blockIdx.z;
    const int n0  = blockIdx.x * 128;
    const int m0  = blockIdx.y * 64;
    const float* X  = inp ? R   : q;
    const float* g  = inp ? gr  : gq;
    const float* b  = inp ? br  : bq;
    const float* W1 = inp ? W1r : W1q;
    const float* b1 = inp ? b1r : b1q;
    const int rbase = inp * NQ;

    __shared__ __align__(16) float Xs[64][36];
    __shared__ __align__(16) float Wk[32][132];
    __shared__ float meanS[64], rstdS[64];

    const int tid = threadIdx.x;
    if (tid < 64){
        meanS[tid] = stats[2 * (rbase + m0 + tid)];
        rstdS[tid] = stats[2 * (rbase + m0 + tid) + 1];
    }
    __syncthreads();

    const int ty = tid >> 4;
    const int tx = tid & 15;

    float acc[4][8];
#pragma unroll
    for (int i = 0; i < 4; ++i)
#pragma unroll
        for (int jj = 0; jj < 8; ++jj) acc[i][jj] = 0.f;

    for (int kc = 0; kc < 64; ++kc){
        const int k0 = kc * 32;
#pragma unroll
        for (int i = 0; i < 8; ++i){
            int e = tid + i * 256;
            int rr = e >> 5, kk = e & 31;
            float xv = X[(size_t)(m0 + rr) * HD + k0 + kk];
            Xs[rr][kk] = (xv - meanS[rr]) * rstdS[rr] * g[k0 + kk] + b[k0 + kk];
        }
#pragma unroll
        for (int i = 0; i < 16; ++i){
            int e = tid + i * 256;
            int nn = e >> 5, kk = e & 31;
            Wk[kk][nn] = W1[(size_t)(n0 + nn) * HD + k0 + kk];
        }
        __syncthreads();
#pragma unroll
        for (int k4 = 0; k4 < 8; ++k4){
            float a0[4][4];
#pragma unroll
            for (int jj = 0; jj < 4; ++jj){
                float4 t0 = *(const float4*)&Xs[ty * 4 + jj][k4 * 4];
                a0[jj][0] = t0.x; a0[jj][1] = t0.y; a0[jj][2] = t0.z; a0[jj][3] = t0.w;
            }
#pragma unroll
            for (int kq = 0; kq < 4; ++kq){
                float4 w0 = *(const float4*)&Wk[k4 * 4 + kq][tx * 8];
                float4 w1 = *(const float4*)&Wk[k4 * 4 + kq][tx * 8 + 4];
                float wv[8] = {w0.x, w0.y, w0.z, w0.w, w1.x, w1.y, w1.z, w1.w};
#pragma unroll
                for (int i = 0; i < 4; ++i){
#pragma unroll
                    for (int jj = 0; jj < 8; ++jj){
                        acc[i][jj] += a0[i][kq] * wv[jj];
                    }
                }
            }
        }
        __syncthreads();
    }
#pragma unroll
    for (int i = 0; i < 4; ++i){
        int rr = ty * 4 + i;
        size_t o = (size_t)(rbase + m0 + rr) * D2 + n0 + tx * 8;
        float h[8];
#pragma unroll
        for (int jj = 0; jj < 8; ++jj)
            h[jj] = gelu_exact(acc[i][jj] + b1[n0 + tx * 8 + jj]);
        float4 o0 = {h[0], h[1], h[2], h[3]};
        float4 o1 = {h[4], h[5], h[6], h[7]};
        *(float4*)&H[o]     = o0;
        *(float4*)&H[o + 4] = o1;
    }
}

// ---------------- K3: GEMM2 + l2norm -> Z (fp32) and Zbf (bf16)
__global__ __launch_bounds__(256)
void k3_gemm2(const float* __restrict__ H,
              const float* __restrict__ W2q, const float* __restrict__ b2q,
              const float* __restrict__ W2r, const float* __restrict__ b2r,
              float* __restrict__ Z, unsigned short* __restrict__ Zbf){
    const int gstart = blockIdx.x * 32;
    const int inp = (gstart >= NQ) ? 1 : 0;
    const float* W2 = inp ? W2r : W2q;
    const float* b2 = inp ? b2r : b2q;

    __shared__ __align__(16) float Hs[32][68];
    __shared__ __align__(16) float Wk[64][132];
    __shared__ float red[32][17];
    __shared__ float normS[32];

    const int tid = threadIdx.x;
    const int ty = tid >> 4;
    const int tx = tid & 15;

    float acc[2][8];
#pragma unroll
    for (int jj = 0; jj < 8; ++jj){ acc[0][jj] = 0.f; acc[1][jj] = 0.f; }

    for (int kc = 0; kc < 4; ++kc){
#pragma unroll
        for (int i = 0; i < 8; ++i){
            int e = tid + i * 256;
            int rr = e >> 6, kk = e & 63;
            Hs[rr][kk] = H[(size_t)(gstart + rr) * D2 + kc * 64 + kk];
        }
#pragma unroll
        for (int i = 0; i < 32; ++i){
            int e = tid + i * 256;
            int nn = e >> 6, kk = e & 63;
            Wk[kk][nn] = W2[(size_t)nn * D2 + kc * 64 + kk];
        }
        __syncthreads();
#pragma unroll
        for (int k4 = 0; k4 < 16; ++k4){
            float a0[4], a1[4];
            float4 t0 = *(const float4*)&Hs[ty * 2][k4 * 4];
            a0[0] = t0.x; a0[1] = t0.y; a0[2] = t0.z; a0[3] = t0.w;
            float4 t1 = *(const float4*)&Hs[ty * 2 + 1][k4 * 4];
            a1[0] = t1.x; a1[1] = t1.y; a1[2] = t1.z; a1[3] = t1.w;
#pragma unroll
            for (int kq = 0; kq < 4; ++kq){
                float4 w0 = *(const float4*)&Wk[k4 * 4 + kq][tx * 8];
                float4 w1 = *(const float4*)&Wk[k4 * 4 + kq][tx * 8 + 4];
                float wv[8] = {w0.x, w0.y, w0.z, w0.w, w1.x, w1.y, w1.z, w1.w};
#pragma unroll
                for (int jj = 0; jj < 8; ++jj){
                    acc[0][jj] += a0[kq] * wv[jj];
                    acc[1][jj] += a1[kq] * wv[jj];
                }
            }
        }
        __syncthreads();
    }
    float v0[8], v1[8];
    float sq0 = 0.f, sq1 = 0.f;
#pragma unroll
    for (int jj = 0; jj < 8; ++jj){
        int c = tx * 8 + jj;
        v0[jj] = acc[0][jj] + b2[c];
        v1[jj] = acc[1][jj] + b2[c];
        sq0 += v0[jj] * v0[jj];
        sq1 += v1[jj] * v1[jj];
    }
    red[ty * 2][tx]     = sq0;
    red[ty * 2 + 1][tx] = sq1;
    __syncthreads();
    if (tid < 32){
        float s = 0.f;
#pragma unroll
        for (int t = 0; t < 16; ++t) s += red[tid][t];
        normS[tid] = 1.0f / fmaxf(sqrtf(s), 1e-12f);
    }
    __syncthreads();
    float s0 = normS[ty * 2], s1 = normS[ty * 2 + 1];
    int row0 = gstart + ty * 2, row1 = row0 + 1;
    size_t o0 = (size_t)row0 * DD + tx * 8;
    size_t o1 = (size_t)row1 * DD + tx * 8;
    float z0[8], z1[8];
#pragma unroll
    for (int jj = 0; jj < 8; ++jj){ z0[jj] = v0[jj] * s0; z1[jj] = v1[jj] * s1; }
    float4 a = {z0[0], z0[1], z0[2], z0[3]}, b = {z0[4], z0[5], z0[6], z0[7]};
    float4 c = {z1[0], z1[1], z1[2], z1[3]}, d = {z1[4], z1[5], z1[6], z1[7]};
    *(float4*)&Z[o0]     = a;  *(float4*)&Z[o0 + 4] = b;
    *(float4*)&Z[o1]     = c;  *(float4*)&Z[o1 + 4] = d;
    uint4 p0 = {pack2bf(z0[0], z0[1]), pack2bf(z0[2], z0[3]),
                pack2bf(z0[4], z0[5]), pack2bf(z0[6], z0[7])};
    uint4 p1 = {pack2bf(z1[0], z1[1]), pack2bf(z1[2], z1[3]),
                pack2bf(z1[4], z1[5]), pack2bf(z1[6], z1[7])};
    *(uint4*)&Zbf[o0] = p0;
    *(uint4*)&Zbf[o1] = p1;
}

// ---------------- KT: ZbfT[d][r] = Zbf[NQ + r][d]  (r part only), tile 64x128.
__global__ __launch_bounds__(256)
void kT_transpose(const unsigned short* __restrict__ Zbf,
                  unsigned short* __restrict__ ZbfT){
    __shared__ unsigned short Ts[64][129];
    const int r0 = blockIdx.x * 64;
    const int tid = threadIdx.x;
#pragma unroll
    for (int i = 0; i < 32; ++i){
        int e = tid + i * 256;
        int rr = e >> 7, dd = e & 127;
        Ts[rr][dd] = Zbf[(size_t)(NQ + r0 + rr) * DD + dd];
    }
    __syncthreads();
#pragma unroll
    for (int i = 0; i < 32; ++i){
        int e = tid + i * 256;
        int dd = e >> 6, rr = e & 63;
        ZbfT[(size_t)dd * NQ + r0 + rr] = Ts[rr][dd];
    }
}

// ---------------- KA: flash attention pass (bf16 MFMA).
// grid (64 m-blocks, 8 r-splits), 256 thr = 4 waves, each wave = 16 q rows.
// Per r-tile (64 r): S = Zq·Zr^T (MFMA), e=exp(s/sqrt D), accumulate l,W;
// P̃=e (bf16) through wave-private LDS (C-layout -> A-layout); O += P̃·Zr (MFMA).
// Outputs fp32 partials OP[split] and (l,W) in LW[split].
__global__ __launch_bounds__(256)
void kA_attn(const unsigned short* __restrict__ Zbf,
             const unsigned short* __restrict__ ZbfT,
             float* __restrict__ OP, float* __restrict__ LW){
    const int tid  = threadIdx.x;
    const int wave = tid >> 6, lane = tid & 63;
    const int quad = lane >> 4, col = lane & 15;
    const int m0   = blockIdx.x * 64 + wave * 16;
    const int split = blockIdx.y;
    const float scl = 0.08838834764831845f;   // 1/sqrt(128)

    __shared__ __align__(16) unsigned short Pt[4][16][72];  // per-wave [m][r]

    s16x8 aq[4];
#pragma unroll
    for (int kb = 0; kb < 4; ++kb)
        aq[kb] = *(const s16x8*)&Zbf[(size_t)(m0 + col) * DD + kb * 32 + quad * 8];

    f32x4 o[8];
#pragma unroll
    for (int dt = 0; dt < 8; ++dt) o[dt] = (f32x4){0.f, 0.f, 0.f, 0.f};
    float lp[4] = {0.f, 0.f, 0.f, 0.f}, wp[4] = {0.f, 0.f, 0.f, 0.f};

    for (int it = 0; it < 8; ++it){
        const int r0 = split * 512 + it * 64;
#pragma unroll
        for (int nt = 0; nt < 4; ++nt){
            f32x4 s = (f32x4){0.f, 0.f, 0.f, 0.f};
#pragma unroll
            for (int kb = 0; kb < 4; ++kb){
                s16x8 b = *(const s16x8*)&Zbf[(size_t)(NQ + r0 + nt * 16 + col) * DD + kb * 32 + quad * 8];
                s = __builtin_amdgcn_mfma_f32_16x16x32_bf16(aq[kb], b, s, 0, 0, 0);
            }
#pragma unroll
            for (int reg = 0; reg < 4; ++reg){
                float sv = s[reg] * scl;              // S[m=quad*4+reg][n=nt*16+col]
                float e  = __expf(sv);
                lp[reg] += e;
                wp[reg] += e * sv;
                Pt[wave][quad * 4 + reg][nt * 16 + col] = f2bf(e);
            }
        }
        s16x8 ap[2];
#pragma unroll
        for (int kb2 = 0; kb2 < 2; ++kb2)
            ap[kb2] = *(const s16x8*)&Pt[wave][col][kb2 * 32 + quad * 8];
#pragma unroll
        for (int dt = 0; dt < 8; ++dt){
#pragma unroll
            for (int kb2 = 0; kb2 < 2; ++kb2){
                s16x8 b = *(const s16x8*)&ZbfT[(size_t)(dt * 16 + col) * NQ + r0 + kb2 * 32 + quad * 8];
                o[dt] = __builtin_amdgcn_mfma_f32_16x16x32_bf16(ap[kb2], b, o[dt], 0, 0, 0);
            }
        }
    }
#pragma unroll
    for (int reg = 0; reg < 4; ++reg){
        float l = lp[reg], w = wp[reg];
        l += __shfl_xor(l, 8);  w += __shfl_xor(w, 8);
        l += __shfl_xor(l, 4);  w += __shfl_xor(w, 4);
        l += __shfl_xor(l, 2);  w += __shfl_xor(w, 2);
        l += __shfl_xor(l, 1);  w += __shfl_xor(w, 1);
        if (col == 0){
            int row = m0 + quad * 4 + reg;
            LW[((size_t)split * NQ + row) * 2]     = l;
            LW[((size_t)split * NQ + row) * 2 + 1] = w;
        }
    }
#pragma unroll
    for (int dt = 0; dt < 8; ++dt){
#pragma unroll
        for (int reg = 0; reg < 4; ++reg){
            int row = m0 + quad * 4 + reg;
            OP[((size_t)split * NQ + row) * DD + dt * 16 + col] = o[dt][reg];
        }
    }
}

// ---------------- KC: combine splits -> r_bar, cos, u_n.
__global__ __launch_bounds__(128)
void kC_combine(const float* __restrict__ OP, const float* __restrict__ LW,
                const float* __restrict__ Z,
                float* __restrict__ RB, float* __restrict__ COS,
                float* __restrict__ ILW){
    const int r = blockIdx.x;
    const int c = threadIdx.x;
    float v = 0.f;
#pragma unroll
    for (int s = 0; s < 8; ++s) v += OP[((size_t)s * NQ + r) * DD + c];
    __shared__ float red[128];
    red[c] = v * v; __syncthreads();
    for (int off = 64; off > 0; off >>= 1){
        if (c < off) red[c] += red[c + off];
        __syncthreads();
    }
    float scale = 1.0f / fmaxf(sqrtf(red[0]), 1e-12f);
    __syncthreads();
    float rb = v * scale;          // l2n(O) == l2n(attn@Zr): 1/l cancels
    RB[(size_t)r * DD + c] = rb;
    float zq = Z[(size_t)r * DD + c];
    red[c] = zq * rb; __syncthreads();
    for (int off = 64; off > 0; off >>= 1){
        if (c < off) red[c] += red[c + off];
        __syncthreads();
    }
    if (c == 0){
        COS[r] = red[0];
        float l = 0.f, w = 0.f;
#pragma unroll
        for (int s = 0; s < 8; ++s){
            l += LW[((size_t)s * NQ + r) * 2];
            w += LW[((size_t)s * NQ + r) * 2 + 1];
        }
        float ent = logf(l) - w / l;
        ILW[2 * r]     = 1.0f / l;
        ILW[2 * r + 1] = ent * (1.0f / 8.317766166719343f);  // / ln(4096)
    }
}

// ---------------- K8: decoder MLP (LN -> 256->128 GELU -> 128->1) + scalar heads
__global__ __launch_bounds__(256)
void k8_decoder(const float* __restrict__ Z, const float* __restrict__ RB,
                const float* __restrict__ ILW, const float* __restrict__ COS,
                const float* __restrict__ gd, const float* __restrict__ bd,
                const float* __restrict__ W1d, const float* __restrict__ b1d,
                const float* __restrict__ W2d, const float* __restrict__ b2d,
                const float* __restrict__ beta, const float* __restrict__ W_len,
                const float* __restrict__ b_len,
                float* __restrict__ out){
    const int r0 = blockIdx.x * 16;
    const int tid = threadIdx.x;

    __shared__ __align__(16) float Xk[256][20];
    __shared__ __align__(16) float Wd[32][132];
    __shared__ float Hd[16][132];
    __shared__ float red1[16][17], red2[16][17];
    __shared__ float mS[16], rS[16];

#pragma unroll
    for (int i = 0; i < 16; ++i){
        int e = tid + i * 256;
        int rr = e >> 8, cc = e & 255;
        float v = (cc < DD) ? Z[(size_t)(r0 + rr) * DD + cc]
                            : RB[(size_t)(r0 + rr) * DD + (cc - DD)];
        Xk[cc][rr] = v;
    }
    __syncthreads();
    {
        const int row = tid >> 4, sub = tid & 15;
        float s = 0.f, sq = 0.f;
#pragma unroll
        for (int i = 0; i < 16; ++i){
            float v = Xk[sub + 16 * i][row];
            s += v; sq += v * v;
        }
        red1[row][sub] = s; red2[row][sub] = sq;
        __syncthreads();
        if (sub == 0){
            float ts = 0.f, tq = 0.f;
#pragma unroll
            for (int t = 0; t < 16; ++t){ ts += red1[row][t]; tq += red2[row][t]; }
            float mean = ts * (1.0f / D2);
            float var  = tq * (1.0f / D2) - mean * mean;
            var = fmaxf(var, 0.f);
            mS[row] = mean; rS[row] = rsqrtf(var + 1e-5f);
        }
        __syncthreads();
    }
#pragma unroll
    for (int i = 0; i < 16; ++i){
        int e = tid + i * 256;
        int rr = e >> 8, cc = e & 255;
        float v = Xk[cc][rr];
        Xk[cc][rr] = (v - mS[rr]) * rS[rr] * gd[cc] + bd[cc];
    }
    __syncthreads();

    const int j  = tid & 127;
    const int rh = tid >> 7;
    float hacc[8];
    {
        float bj = b1d[j];
#pragma unroll
        for (int i = 0; i < 8; ++i) hacc[i] = bj;
    }
    for (int kc = 0; kc < 8; ++kc){
#pragma unroll
        for (int i = 0; i < 16; ++i){
            int e = tid + i * 256;
            int nn = e >> 5, kk = e & 31;
            Wd[kk][nn] = W1d[(size_t)nn * D2 + kc * 32 + kk];
        }
        __syncthreads();
#pragma unroll
        for (int k = 0; k < 32; ++k){
            float w = Wd[k][j];
            int kk = kc * 32 + k;
            float4 x0 = *(const float4*)&Xk[kk][rh * 8];
            float4 x1 = *(const float4*)&Xk[kk][rh * 8 + 4];
            hacc[0] += x0.x * w; hacc[1] += x0.y * w;
            hacc[2] += x0.z * w; hacc[3] += x0.w * w;
            hacc[4] += x1.x * w; hacc[5] += x1.y * w;
            hacc[6] += x1.z * w; hacc[7] += x1.w * w;
        }
        __syncthreads();
    }
#pragma unroll
    for (int i = 0; i < 8; ++i) Hd[rh * 8 + i][j] = gelu_exact(hacc[i]);
    __syncthreads();
    {
        const int row = tid >> 4, sub = tid & 15;
        float part = 0.f;
#pragma unroll
        for (int i = 0; i < 8; ++i){
            int jj = sub + 16 * i;
            part += Hd[row][jj] * W2d[jj];
        }
        red1[row][sub] = part;
        __syncthreads();
        if (sub == 0){
            float lg = b2d[0];
#pragma unroll
            for (int t = 0; t < 16; ++t) lg += red1[row][t];
            int gr = r0 + row;
            float u  = ILW[2 * gr + 1];
            float cv = COS[gr];
            float dln = cv * W_len[0] + u * W_len[1] + b_len[0];
            float dt = beta[0] * u + beta[1] * tanhf(dln);
            dt = fminf(0.5f, fmaxf(-0.5f, dt));
            out[gr]      = lg;
            out[NQ + gr] = dt;
        }
    }
}

extern "C" void kernel_launch(void* const* d_in, const int* in_sizes, int n_in,
                              void* d_out, int out_size, void* d_ws, size_t ws_size,
                              hipStream_t stream){
    const float* q      = (const float*)d_in[0];
    const float* R      = (const float*)d_in[1];
    const float* ln_q_g = (const float*)d_in[2];
    const float* ln_q_b = (const float*)d_in[3];
    const float* W1q    = (const float*)d_in[4];
    const float* b1q    = (const float*)d_in[5];
    const float* W2q    = (const float*)d_in[6];
    const float* b2q    = (const float*)d_in[7];
    const float* ln_r_g = (const float*)d_in[8];
    const float* ln_r_b = (const float*)d_in[9];
    const float* W1r    = (const float*)d_in[10];
    const float* b1r    = (const float*)d_in[11];
    const float* W2r    = (const float*)d_in[12];
    const float* b2r    = (const float*)d_in[13];
    const float* ln_d_g = (const float*)d_in[14];
    const float* ln_d_b = (const float*)d_in[15];
    const float* W1d    = (const float*)d_in[16];
    const float* b1d    = (const float*)d_in[17];
    const float* W2d    = (const float*)d_in[18];
    const float* b2d    = (const float*)d_in[19];
    const float* beta   = (const float*)d_in[20];
    const float* W_len  = (const float*)d_in[21];
    const float* b_len  = (const float*)d_in[22];

    float* WS = (float*)d_ws;
    float* stats = WS;                                  // 16384
    float* Z     = WS + 16384;                          // 1048576
    unsigned short* Zbf  = (unsigned short*)(WS + 1064960);   // 8192*128 bf16
    unsigned short* ZbfT = (unsigned short*)(WS + 1589248);   // 128*4096 bf16
    float* RB    = WS + 1851392;                        // 524288
    float* COSV  = WS + 2375680;                        // 4096
    float* ILW   = WS + 2379776;                        // 8192
    float* H     = WS + 2387968;                        // 2097152 (aliased w/ OP)
    float* OP    = WS + 2387968;                        // 4194304
    float* LW    = OP + (size_t)8 * NQ * DD;            // 65536
    float* out   = (float*)d_out;

    hipLaunchKernelGGL(k1_ln_stats, dim3(NT), dim3(256), 0, stream, q, R, stats);
    hipLaunchKernelGGL(k2_gemm1_gelu, dim3(2, 64, 2), dim3(256), 0, stream,
                       q, R, stats, ln_q_g, ln_q_b, W1q, b1q, ln_r_g, ln_r_b, W1r, b1r, H);
    hipLaunchKernelGGL(k3_gemm2, dim3(256), dim3(256), 0, stream,
                       H, W2q, b2q, W2r, b2r, Z, Zbf);
    hipLaunchKernelGGL(kT_transpose, dim3(64), dim3(256), 0, stream, Zbf, ZbfT);
    hipLaunchKernelGGL(kA_attn, dim3(64, 8), dim3(256), 0, stream, Zbf, ZbfT, OP, LW);
    hipLaunchKernelGGL(kC_combine, dim3(NQ), dim3(128), 0, stream, OP, LW, Z, RB, COSV, ILW);
    hipLaunchKernelGGL(k8_decoder, dim3(256), dim3(256), 0, stream,
                       Z, RB, ILW, COSV, ln_d_g, ln_d_b, W1d, b1d, W2d, b2d,
                       beta, W_len, b_len, out);
}

// Round 8
// 352.976 us; speedup vs baseline: 1.8196x; 1.2785x over previous
//
#include <hip/hip_runtime.h>
#include <math.h>

// RouterLite v6.1 = v6 with the workspace aliasing bug fixed: Xbf is
// 8,388,608 floats of space (16.8M bf16), not 4,194,304 — v6 placed HP inside
// live Xbf (k2 wrote partials over the R rows it was still reading -> NaN).
// Kernels unchanged from v6.
//
// ws map (float offsets), total ~61.9 MB:
//   Xbf  @0         [8192][2048] bf16 (8388608 fl) — dead after k2_mfma,
//                   ALIASED by OP @0 [8][4096][128] fp32 + LW @4194304 [8][4096][2]
//   HP   @8388608   [2][8192][256] fp32 partials (k2->k3, dead after)
//   Wbf  @12582912  [512][2048] bf16 (W1q rows 0..255, W1r 256..511)
//   Z    @13107200  [8192][128] fp32
//   Zbf  @14155776  [8192][128] bf16
//   ZbfT @14680064  [128][4096] bf16 (Z_r transposed)
//   RB   @14942208  [4096][128]
//   COS  @15466496  [4096]
//   ILW  @15470592  [4096][2]
// d_out: fp32, [0..4095]=raw_logit, [4096..8191]=delta_theta.

#define HD   2048
#define D2   256
#define DD   128
#define NQ   4096
#define NT   8192

typedef __attribute__((ext_vector_type(8))) short s16x8;
typedef __attribute__((ext_vector_type(4))) float f32x4;

static __device__ __forceinline__ float gelu_exact(float x){
    return 0.5f * x * (1.0f + erff(x * 0.7071067811865475f));
}
static __device__ __forceinline__ unsigned short f2bf(float f){
    unsigned int u = __float_as_uint(f);
    return (unsigned short)((u + 0x7FFFu + ((u >> 16) & 1u)) >> 16);
}
static __device__ __forceinline__ unsigned int pack2bf(float a, float b){
    return (unsigned int)f2bf(a) | ((unsigned int)f2bf(b) << 16);
}

// ---------------- KLN: LN(x) -> bf16 Xbf (blocks 0..8191); W1 -> bf16 Wbf (8192..8703)
__global__ __launch_bounds__(256)
void kLN_cast(const float* __restrict__ q, const float* __restrict__ R,
              const float* __restrict__ gq, const float* __restrict__ bq,
              const float* __restrict__ gr, const float* __restrict__ br,
              const float* __restrict__ W1q, const float* __restrict__ W1r,
              unsigned short* __restrict__ Xbf, unsigned short* __restrict__ Wbf){
    const int r = blockIdx.x;
    const int tid = threadIdx.x;
    if (r >= NT){
        const int rw = r - NT;
        const float* src = (rw >= 256) ? (W1r + (size_t)(rw - 256) * HD)
                                       : (W1q + (size_t)rw * HD);
        float4 a = *(const float4*)&src[tid * 8];
        float4 c = *(const float4*)&src[tid * 8 + 4];
        uint4 p = {pack2bf(a.x, a.y), pack2bf(a.z, a.w),
                   pack2bf(c.x, c.y), pack2bf(c.z, c.w)};
        *(uint4*)&Wbf[(size_t)rw * HD + tid * 8] = p;
        return;
    }
    const float* src = (r < NQ) ? (q + (size_t)r * HD) : (R + (size_t)(r - NQ) * HD);
    const float* g  = (r < NQ) ? gq : gr;
    const float* bb = (r < NQ) ? bq : br;
    float4 x0 = *(const float4*)&src[tid * 8];
    float4 x1 = *(const float4*)&src[tid * 8 + 4];
    float v[8] = {x0.x, x0.y, x0.z, x0.w, x1.x, x1.y, x1.z, x1.w};
    float s = 0.f, sq = 0.f;
#pragma unroll
    for (int i = 0; i < 8; ++i){ s += v[i]; sq += v[i] * v[i]; }
    __shared__ float red[256];
    __shared__ float mS, rS;
    red[tid] = s; __syncthreads();
    for (int off = 128; off > 0; off >>= 1){
        if (tid < off) red[tid] += red[tid + off];
        __syncthreads();
    }
    float sum = red[0]; __syncthreads();
    red[tid] = sq; __syncthreads();
    for (int off = 128; off > 0; off >>= 1){
        if (tid < off) red[tid] += red[tid + off];
        __syncthreads();
    }
    if (tid == 0){
        float mean = sum * (1.0f / HD);
        float var  = red[0] * (1.0f / HD) - mean * mean;
        mS = mean;
        rS = rsqrtf(fmaxf(var, 0.0f) + 1e-5f);
    }
    __syncthreads();
    float mean = mS, rstd = rS;
    float4 g0 = *(const float4*)&g[tid * 8];
    float4 g1 = *(const float4*)&g[tid * 8 + 4];
    float4 b0 = *(const float4*)&bb[tid * 8];
    float4 b1 = *(const float4*)&bb[tid * 8 + 4];
    float gg[8] = {g0.x, g0.y, g0.z, g0.w, g1.x, g1.y, g1.z, g1.w};
    float bv[8] = {b0.x, b0.y, b0.z, b0.w, b1.x, b1.y, b1.z, b1.w};
    float h[8];
#pragma unroll
    for (int i = 0; i < 8; ++i) h[i] = (v[i] - mean) * rstd * gg[i] + bv[i];
    uint4 p = {pack2bf(h[0], h[1]), pack2bf(h[2], h[3]),
               pack2bf(h[4], h[5]), pack2bf(h[6], h[7])};
    *(uint4*)&Xbf[(size_t)r * HD + tid * 8] = p;
}

// ---------------- K2: HP[ks] = Xbf @ Wbf^T (K-half ks), bf16 MFMA.
// grid (128 m-blocks of 64, 2 n-blocks of 128, 2 K-splits), 256 thr = 4 waves.
// Wave: 32m x 64n = 2x4 tiles of 16x16. Direct global s16x8 fragment loads.
__global__ __launch_bounds__(256)
void k2_mfma(const unsigned short* __restrict__ Xbf,
             const unsigned short* __restrict__ Wbf,
             float* __restrict__ HP){
    const int tid  = threadIdx.x;
    const int wave = tid >> 6, lane = tid & 63;
    const int quad = lane >> 4, col = lane & 15;
    const int mblk = blockIdx.x;
    const int nblk = blockIdx.y;
    const int ks   = blockIdx.z;
    const int inp  = mblk >> 6;
    const int mbase = mblk * 64 + (wave & 1) * 32;
    const int nbase = nblk * 128 + (wave >> 1) * 64;

    const unsigned short* A0 = Xbf + (size_t)(mbase + col) * HD + ks * 1024 + quad * 8;
    const unsigned short* A1 = A0 + (size_t)16 * HD;
    const unsigned short* B0 = Wbf + (size_t)(inp * 256 + nbase + col) * HD + ks * 1024 + quad * 8;
    const unsigned short* B1 = B0 + (size_t)16 * HD;
    const unsigned short* B2 = B0 + (size_t)32 * HD;
    const unsigned short* B3 = B0 + (size_t)48 * HD;

    f32x4 acc[2][4];
#pragma unroll
    for (int mi = 0; mi < 2; ++mi)
#pragma unroll
        for (int ni = 0; ni < 4; ++ni) acc[mi][ni] = (f32x4){0.f, 0.f, 0.f, 0.f};

    for (int s = 0; s < 32; ++s){
        const int ko = s * 32;
        s16x8 a0 = *(const s16x8*)(A0 + ko);
        s16x8 a1 = *(const s16x8*)(A1 + ko);
        s16x8 b0 = *(const s16x8*)(B0 + ko);
        s16x8 b1 = *(const s16x8*)(B1 + ko);
        s16x8 b2 = *(const s16x8*)(B2 + ko);
        s16x8 b3 = *(const s16x8*)(B3 + ko);
        acc[0][0] = __builtin_amdgcn_mfma_f32_16x16x32_bf16(a0, b0, acc[0][0], 0, 0, 0);
        acc[0][1] = __builtin_amdgcn_mfma_f32_16x16x32_bf16(a0, b1, acc[0][1], 0, 0, 0);
        acc[0][2] = __builtin_amdgcn_mfma_f32_16x16x32_bf16(a0, b2, acc[0][2], 0, 0, 0);
        acc[0][3] = __builtin_amdgcn_mfma_f32_16x16x32_bf16(a0, b3, acc[0][3], 0, 0, 0);
        acc[1][0] = __builtin_amdgcn_mfma_f32_16x16x32_bf16(a1, b0, acc[1][0], 0, 0, 0);
        acc[1][1] = __builtin_amdgcn_mfma_f32_16x16x32_bf16(a1, b1, acc[1][1], 0, 0, 0);
        acc[1][2] = __builtin_amdgcn_mfma_f32_16x16x32_bf16(a1, b2, acc[1][2], 0, 0, 0);
        acc[1][3] = __builtin_amdgcn_mfma_f32_16x16x32_bf16(a1, b3, acc[1][3], 0, 0, 0);
    }
    float* dst = HP + (size_t)ks * NT * D2;
#pragma unroll
    for (int mi = 0; mi < 2; ++mi){
#pragma unroll
        for (int ni = 0; ni < 4; ++ni){
#pragma unroll
            for (int reg = 0; reg < 4; ++reg){
                int m = mbase + mi * 16 + quad * 4 + reg;
                int n = nbase + ni * 16 + col;
                dst[(size_t)m * D2 + n] = acc[mi][ni][reg];
            }
        }
    }
}

// ---------------- K3: combine HP + bias + GELU, GEMM2, l2norm -> Z (fp32), Zbf (bf16)
__global__ __launch_bounds__(256)
void k3_gemm2(const float* __restrict__ HP,
              const float* __restrict__ b1q, const float* __restrict__ b1r,
              const float* __restrict__ W2q, const float* __restrict__ b2q,
              const float* __restrict__ W2r, const float* __restrict__ b2r,
              float* __restrict__ Z, unsigned short* __restrict__ Zbf){
    const int gstart = blockIdx.x * 32;
    const int inp = (gstart >= NQ) ? 1 : 0;
    const float* b1 = inp ? b1r : b1q;
    const float* W2 = inp ? W2r : W2q;
    const float* b2 = inp ? b2r : b2q;

    __shared__ __align__(16) float Hs[32][68];
    __shared__ __align__(16) float Wk[64][132];
    __shared__ float red[32][17];
    __shared__ float normS[32];

    const int tid = threadIdx.x;
    const int ty = tid >> 4;
    const int tx = tid & 15;

    float acc[2][8];
#pragma unroll
    for (int jj = 0; jj < 8; ++jj){ acc[0][jj] = 0.f; acc[1][jj] = 0.f; }

    for (int kc = 0; kc < 4; ++kc){
#pragma unroll
        for (int i = 0; i < 8; ++i){
            int e = tid + i * 256;
            int rr = e >> 6, kk = e & 63;
            size_t idx = (size_t)(gstart + rr) * D2 + kc * 64 + kk;
            float hv = HP[idx] + HP[(size_t)NT * D2 + idx] + b1[kc * 64 + kk];
            Hs[rr][kk] = gelu_exact(hv);
        }
#pragma unroll
        for (int i = 0; i < 32; ++i){
            int e = tid + i * 256;
            int nn = e >> 6, kk = e & 63;
            Wk[kk][nn] = W2[(size_t)nn * D2 + kc * 64 + kk];
        }
        __syncthreads();
#pragma unroll
        for (int k4 = 0; k4 < 16; ++k4){
            float a0[4], a1[4];
            float4 t0 = *(const float4*)&Hs[ty * 2][k4 * 4];
            a0[0] = t0.x; a0[1] = t0.y; a0[2] = t0.z; a0[3] = t0.w;
            float4 t1 = *(const float4*)&Hs[ty * 2 + 1][k4 * 4];
            a1[0] = t1.x; a1[1] = t1.y; a1[2] = t1.z; a1[3] = t1.w;
#pragma unroll
            for (int kq = 0; kq < 4; ++kq){
                float4 w0 = *(const float4*)&Wk[k4 * 4 + kq][tx * 8];
                float4 w1 = *(const float4*)&Wk[k4 * 4 + kq][tx * 8 + 4];
                float wv[8] = {w0.x, w0.y, w0.z, w0.w, w1.x, w1.y, w1.z, w1.w};
#pragma unroll
                for (int jj = 0; jj < 8; ++jj){
                    acc[0][jj] += a0[kq] * wv[jj];
                    acc[1][jj] += a1[kq] * wv[jj];
                }
            }
        }
        __syncthreads();
    }
    float v0[8], v1[8];
    float sq0 = 0.f, sq1 = 0.f;
#pragma unroll
    for (int jj = 0; jj < 8; ++jj){
        int c = tx * 8 + jj;
        v0[jj] = acc[0][jj] + b2[c];
        v1[jj] = acc[1][jj] + b2[c];
        sq0 += v0[jj] * v0[jj];
        sq1 += v1[jj] * v1[jj];
    }
    red[ty * 2][tx]     = sq0;
    red[ty * 2 + 1][tx] = sq1;
    __syncthreads();
    if (tid < 32){
        float s = 0.f;
#pragma unroll
        for (int t = 0; t < 16; ++t) s += red[tid][t];
        normS[tid] = 1.0f / fmaxf(sqrtf(s), 1e-12f);
    }
    __syncthreads();
    float s0 = normS[ty * 2], s1 = normS[ty * 2 + 1];
    int row0 = gstart + ty * 2, row1 = row0 + 1;
    size_t o0 = (size_t)row0 * DD + tx * 8;
    size_t o1 = (size_t)row1 * DD + tx * 8;
    float z0[8], z1[8];
#pragma unroll
    for (int jj = 0; jj < 8; ++jj){ z0[jj] = v0[jj] * s0; z1[jj] = v1[jj] * s1; }
    float4 a = {z0[0], z0[1], z0[2], z0[3]}, b = {z0[4], z0[5], z0[6], z0[7]};
    float4 c = {z1[0], z1[1], z1[2], z1[3]}, d = {z1[4], z1[5], z1[6], z1[7]};
    *(float4*)&Z[o0]     = a;  *(float4*)&Z[o0 + 4] = b;
    *(float4*)&Z[o1]     = c;  *(float4*)&Z[o1 + 4] = d;
    uint4 p0 = {pack2bf(z0[0], z0[1]), pack2bf(z0[2], z0[3]),
                pack2bf(z0[4], z0[5]), pack2bf(z0[6], z0[7])};
    uint4 p1 = {pack2bf(z1[0], z1[1]), pack2bf(z1[2], z1[3]),
                pack2bf(z1[4], z1[5]), pack2bf(z1[6], z1[7])};
    *(uint4*)&Zbf[o0] = p0;
    *(uint4*)&Zbf[o1] = p1;
}

// ---------------- KT: ZbfT[d][r] = Zbf[NQ + r][d]  (r part only), tile 64x128.
__global__ __launch_bounds__(256)
void kT_transpose(const unsigned short* __restrict__ Zbf,
                  unsigned short* __restrict__ ZbfT){
    __shared__ unsigned short Ts[64][129];
    const int r0 = blockIdx.x * 64;
    const int tid = threadIdx.x;
#pragma unroll
    for (int i = 0; i < 32; ++i){
        int e = tid + i * 256;
        int rr = e >> 7, dd = e & 127;
        Ts[rr][dd] = Zbf[(size_t)(NQ + r0 + rr) * DD + dd];
    }
    __syncthreads();
#pragma unroll
    for (int i = 0; i < 32; ++i){
        int e = tid + i * 256;
        int dd = e >> 6, rr = e & 63;
        ZbfT[(size_t)dd * NQ + r0 + rr] = Ts[rr][dd];
    }
}

// ---------------- KA: flash attention pass (bf16 MFMA). Unchanged from v5.1.
__global__ __launch_bounds__(256)
void kA_attn(const unsigned short* __restrict__ Zbf,
             const unsigned short* __restrict__ ZbfT,
             float* __restrict__ OP, float* __restrict__ LW){
    const int tid  = threadIdx.x;
    const int wave = tid >> 6, lane = tid & 63;
    const int quad = lane >> 4, col = lane & 15;
    const int m0   = blockIdx.x * 64 + wave * 16;
    const int split = blockIdx.y;
    const float scl = 0.08838834764831845f;   // 1/sqrt(128)

    __shared__ __align__(16) unsigned short Pt[4][16][72];  // per-wave [m][r]

    s16x8 aq[4];
#pragma unroll
    for (int kb = 0; kb < 4; ++kb)
        aq[kb] = *(const s16x8*)&Zbf[(size_t)(m0 + col) * DD + kb * 32 + quad * 8];

    f32x4 o[8];
#pragma unroll
    for (int dt = 0; dt < 8; ++dt) o[dt] = (f32x4){0.f, 0.f, 0.f, 0.f};
    float lp[4] = {0.f, 0.f, 0.f, 0.f}, wp[4] = {0.f, 0.f, 0.f, 0.f};

    for (int it = 0; it < 8; ++it){
        const int r0 = split * 512 + it * 64;
#pragma unroll
        for (int nt = 0; nt < 4; ++nt){
            f32x4 s = (f32x4){0.f, 0.f, 0.f, 0.f};
#pragma unroll
            for (int kb = 0; kb < 4; ++kb){
                s16x8 b = *(const s16x8*)&Zbf[(size_t)(NQ + r0 + nt * 16 + col) * DD + kb * 32 + quad * 8];
                s = __builtin_amdgcn_mfma_f32_16x16x32_bf16(aq[kb], b, s, 0, 0, 0);
            }
#pragma unroll
            for (int reg = 0; reg < 4; ++reg){
                float sv = s[reg] * scl;
                float e  = __expf(sv);
                lp[reg] += e;
                wp[reg] += e * sv;
                Pt[wave][quad * 4 + reg][nt * 16 + col] = f2bf(e);
            }
        }
        s16x8 ap[2];
#pragma unroll
        for (int kb2 = 0; kb2 < 2; ++kb2)
            ap[kb2] = *(const s16x8*)&Pt[wave][col][kb2 * 32 + quad * 8];
#pragma unroll
        for (int dt = 0; dt < 8; ++dt){
#pragma unroll
            for (int kb2 = 0; kb2 < 2; ++kb2){
                s16x8 b = *(const s16x8*)&ZbfT[(size_t)(dt * 16 + col) * NQ + r0 + kb2 * 32 + quad * 8];
                o[dt] = __builtin_amdgcn_mfma_f32_16x16x32_bf16(ap[kb2], b, o[dt], 0, 0, 0);
            }
        }
    }
#pragma unroll
    for (int reg = 0; reg < 4; ++reg){
        float l = lp[reg], w = wp[reg];
        l += __shfl_xor(l, 8);  w += __shfl_xor(w, 8);
        l += __shfl_xor(l, 4);  w += __shfl_xor(w, 4);
        l += __shfl_xor(l, 2);  w += __shfl_xor(w, 2);
        l += __shfl_xor(l, 1);  w += __shfl_xor(w, 1);
        if (col == 0){
            int row = m0 + quad * 4 + reg;
            LW[((size_t)split * NQ + row) * 2]     = l;
            LW[((size_t)split * NQ + row) * 2 + 1] = w;
        }
    }
#pragma unroll
    for (int dt = 0; dt < 8; ++dt){
#pragma unroll
        for (int reg = 0; reg < 4; ++reg){
            int row = m0 + quad * 4 + reg;
            OP[((size_t)split * NQ + row) * DD + dt * 16 + col] = o[dt][reg];
        }
    }
}

// ---------------- KC: combine splits -> r_bar, cos, u_n.
__global__ __launch_bounds__(128)
void kC_combine(const float* __restrict__ OP, const float* __restrict__ LW,
                const float* __restrict__ Z,
                float* __restrict__ RB, float* __restrict__ COS,
                float* __restrict__ ILW){
    const int r = blockIdx.x;
    const int c = threadIdx.x;
    float v = 0.f;
#pragma unroll
    for (int s = 0; s < 8; ++s) v += OP[((size_t)s * NQ + r) * DD + c];
    __shared__ float red[128];
    red[c] = v * v; __syncthreads();
    for (int off = 64; off > 0; off >>= 1){
        if (c < off) red[c] += red[c + off];
        __syncthreads();
    }
    float scale = 1.0f / fmaxf(sqrtf(red[0]), 1e-12f);
    __syncthreads();
    float rb = v * scale;
    RB[(size_t)r * DD + c] = rb;
    float zq = Z[(size_t)r * DD + c];
    red[c] = zq * rb; __syncthreads();
    for (int off = 64; off > 0; off >>= 1){
        if (c < off) red[c] += red[c + off];
        __syncthreads();
    }
    if (c == 0){
        COS[r] = red[0];
        float l = 0.f, w = 0.f;
#pragma unroll
        for (int s = 0; s < 8; ++s){
            l += LW[((size_t)s * NQ + r) * 2];
            w += LW[((size_t)s * NQ + r) * 2 + 1];
        }
        float ent = logf(l) - w / l;
        ILW[2 * r]     = 1.0f / l;
        ILW[2 * r + 1] = ent * (1.0f / 8.317766166719343f);  // / ln(4096)
    }
}

// ---------------- K8: decoder MLP (LN -> 256->128 GELU -> 128->1) + scalar heads
__global__ __launch_bounds__(256)
void k8_decoder(const float* __restrict__ Z, const float* __restrict__ RB,
                const float* __restrict__ ILW, const float* __restrict__ COS,
                const float* __restrict__ gd, const float* __restrict__ bd,
                const float* __restrict__ W1d, const float* __restrict__ b1d,
                const float* __restrict__ W2d, const float* __restrict__ b2d,
                const float* __restrict__ beta, const float* __restrict__ W_len,
                const float* __restrict__ b_len,
                float* __restrict__ out){
    const int r0 = blockIdx.x * 16;
    const int tid = threadIdx.x;

    __shared__ __align__(16) float Xk[256][20];
    __shared__ __align__(16) float Wd[32][132];
    __shared__ float Hd[16][132];
    __shared__ float red1[16][17], red2[16][17];
    __shared__ float mS[16], rS[16];

#pragma unroll
    for (int i = 0; i < 16; ++i){
        int e = tid + i * 256;
        int rr = e >> 8, cc = e & 255;
        float v = (cc < DD) ? Z[(size_t)(r0 + rr) * DD + cc]
                            : RB[(size_t)(r0 + rr) * DD + (cc - DD)];
        Xk[cc][rr] = v;
    }
    __syncthreads();
    {
        const int row = tid >> 4, sub = tid & 15;
        float s = 0.f, sq = 0.f;
#pragma unroll
        for (int i = 0; i < 16; ++i){
            float v = Xk[sub + 16 * i][row];
            s += v; sq += v * v;
        }
        red1[row][sub] = s; red2[row][sub] = sq;
        __syncthreads();
        if (sub == 0){
            float ts = 0.f, tq = 0.f;
#pragma unroll
            for (int t = 0; t < 16; ++t){ ts += red1[row][t]; tq += red2[row][t]; }
            float mean = ts * (1.0f / D2);
            float var  = tq * (1.0f / D2) - mean * mean;
            var = fmaxf(var, 0.f);
            mS[row] = mean; rS[row] = rsqrtf(var + 1e-5f);
        }
        __syncthreads();
    }
#pragma unroll
    for (int i = 0; i < 16; ++i){
        int e = tid + i * 256;
        int rr = e >> 8, cc = e & 255;
        float v = Xk[cc][rr];
        Xk[cc][rr] = (v - mS[rr]) * rS[rr] * gd[cc] + bd[cc];
    }
    __syncthreads();

    const int j  = tid & 127;
    const int rh = tid >> 7;
    float hacc[8];
    {
        float bj = b1d[j];
#pragma unroll
        for (int i = 0; i < 8; ++i) hacc[i] = bj;
    }
    for (int kc = 0; kc < 8; ++kc){
#pragma unroll
        for (int i = 0; i < 16; ++i){
            int e = tid + i * 256;
            int nn = e >> 5, kk = e & 31;
            Wd[kk][nn] = W1d[(size_t)nn * D2 + kc * 32 + kk];
        }
        __syncthreads();
#pragma unroll
        for (int k = 0; k < 32; ++k){
            float w = Wd[k][j];
            int kk = kc * 32 + k;
            float4 x0 = *(const float4*)&Xk[kk][rh * 8];
            float4 x1 = *(const float4*)&Xk[kk][rh * 8 + 4];
            hacc[0] += x0.x * w; hacc[1] += x0.y * w;
            hacc[2] += x0.z * w; hacc[3] += x0.w * w;
            hacc[4] += x1.x * w; hacc[5] += x1.y * w;
            hacc[6] += x1.z * w; hacc[7] += x1.w * w;
        }
        __syncthreads();
    }
#pragma unroll
    for (int i = 0; i < 8; ++i) Hd[rh * 8 + i][j] = gelu_exact(hacc[i]);
    __syncthreads();
    {
        const int row = tid >> 4, sub = tid & 15;
        float part = 0.f;
#pragma unroll
        for (int i = 0; i < 8; ++i){
            int jj = sub + 16 * i;
            part += Hd[row][jj] * W2d[jj];
        }
        red1[row][sub] = part;
        __syncthreads();
        if (sub == 0){
            float lg = b2d[0];
#pragma unroll
            for (int t = 0; t < 16; ++t) lg += red1[row][t];
            int gr = r0 + row;
            float u  = ILW[2 * gr + 1];
            float cv = COS[gr];
            float dln = cv * W_len[0] + u * W_len[1] + b_len[0];
            float dt = beta[0] * u + beta[1] * tanhf(dln);
            dt = fminf(0.5f, fmaxf(-0.5f, dt));
            out[gr]      = lg;
            out[NQ + gr] = dt;
        }
    }
}

extern "C" void kernel_launch(void* const* d_in, const int* in_sizes, int n_in,
                              void* d_out, int out_size, void* d_ws, size_t ws_size,
                              hipStream_t stream){
    const float* q      = (const float*)d_in[0];
    const float* R      = (const float*)d_in[1];
    const float* ln_q_g = (const float*)d_in[2];
    const float* ln_q_b = (const float*)d_in[3];
    const float* W1q    = (const float*)d_in[4];
    const float* b1q    = (const float*)d_in[5];
    const float* W2q    = (const float*)d_in[6];
    const float* b2q    = (const float*)d_in[7];
    const float* ln_r_g = (const float*)d_in[8];
    const float* ln_r_b = (const float*)d_in[9];
    const float* W1r    = (const float*)d_in[10];
    const float* b1r    = (const float*)d_in[11];
    const float* W2r    = (const float*)d_in[12];
    const float* b2r    = (const float*)d_in[13];
    const float* ln_d_g = (const float*)d_in[14];
    const float* ln_d_b = (const float*)d_in[15];
    const float* W1d    = (const float*)d_in[16];
    const float* b1d    = (const float*)d_in[17];
    const float* W2d    = (const float*)d_in[18];
    const float* b2d    = (const float*)d_in[19];
    const float* beta   = (const float*)d_in[20];
    const float* W_len  = (const float*)d_in[21];
    const float* b_len  = (const float*)d_in[22];

    float* WS = (float*)d_ws;
    unsigned short* Xbf  = (unsigned short*)(WS);             // 8192*2048 bf16 = 8388608 fl
    float* OP    = WS;                                        // aliases Xbf (dead after k2)
    float* LW    = WS + 4194304;                              // 8*4096*2 (inside dead Xbf)
    float* HP    = WS + 8388608;                              // 2*8192*256
    unsigned short* Wbf  = (unsigned short*)(WS + 12582912);  // 512*2048 bf16
    float* Z     = WS + 13107200;                             // 8192*128
    unsigned short* Zbf  = (unsigned short*)(WS + 14155776);  // 8192*128 bf16
    unsigned short* ZbfT = (unsigned short*)(WS + 14680064);  // 128*4096 bf16
    float* RB    = WS + 14942208;                             // 4096*128
    float* COSV  = WS + 15466496;                             // 4096
    float* ILW   = WS + 15470592;                             // 4096*2
    float* out   = (float*)d_out;

    hipLaunchKernelGGL(kLN_cast, dim3(NT + 512), dim3(256), 0, stream,
                       q, R, ln_q_g, ln_q_b, ln_r_g, ln_r_b, W1q, W1r, Xbf, Wbf);
    hipLaunchKernelGGL(k2_mfma, dim3(128, 2, 2), dim3(256), 0, stream, Xbf, Wbf, HP);
    hipLaunchKernelGGL(k3_gemm2, dim3(256), dim3(256), 0, stream,
                       HP, b1q, b1r, W2q, b2q, W2r, b2r, Z, Zbf);
    hipLaunchKernelGGL(kT_transpose, dim3(64), dim3(256), 0, stream, Zbf, ZbfT);
    hipLaunchKernelGGL(kA_attn, dim3(64, 8), dim3(256), 0, stream, Zbf, ZbfT, OP, LW);
    hipLaunchKernelGGL(kC_combine, dim3(NQ), dim3(128), 0, stream, OP, LW, Z, RB, COSV, ILW);
    hipLaunchKernelGGL(k8_decoder, dim3(256), dim3(256), 0, stream,
                       Z, RB, ILW, COSV, ln_d_g, ln_d_b, W1d, b1d, W2d, b2d,
                       beta, W_len, b_len, out);
}